// Round 1
// baseline (198.381 us; speedup 1.0000x reference)
//
#include <hip/hip_runtime.h>

// Problem constants (match reference)
#define HH 50
#define WW 50
#define EPSF 1e-8f

// Binning resolution: x (birth_norm) in [0,1) -> BX bins; y (pers_norm) in (-1,1) -> BY bins
#define BX 512
#define BY 1024

// ws layout (float offsets)
//   hist   : [0, BX*BY)                      512*1024 = 524288
//   gx_tab : [GXOFF, +WW*BX)                 50*512   = 25600   gx_tab[w*BX+ix]
//   gy_tab : [GYOFF, +HH*BY)                 50*1024  = 51200   gy_tab[h*BY+iy]
//   P      : [POFF, +BY*WW)                  1024*50  = 51200   P[iy*WW+w]
//   img    : [IMGOFF, +HH*WW)                2500
#define GXOFF  (BX*BY)
#define GYOFF  (GXOFF + WW*BX)
#define POFF   (GYOFF + HH*BY)
#define IMGOFF (POFF + BY*WW)
#define WS_FLOATS (IMGOFF + HH*WW)

// ---------------------------------------------------------------------------
// Kernel 1: zero the histogram and build the exp lookup tables.
// ---------------------------------------------------------------------------
__global__ void pie_init(float* __restrict__ ws,
                         const float* __restrict__ grid_x,
                         const float* __restrict__ grid_y,
                         const float* __restrict__ sigma_p) {
    const int tid    = blockIdx.x * blockDim.x + threadIdx.x;
    const int stride = gridDim.x * blockDim.x;
    const float s  = *sigma_p;
    const float a  = 1.0f / (2.0f * s * s);

    // zero histogram (d_ws is poisoned 0xAA before every call)
    for (int i = tid; i < BX * BY; i += stride) ws[i] = 0.0f;

    // gx table: bin centers c = (ix+0.5)/BX over [0,1)
    for (int i = tid; i < WW * BX; i += stride) {
        const int w = i / BX, ix = i - w * BX;
        const float c = (ix + 0.5f) * (1.0f / BX);
        const float d = grid_x[w] - c;
        ws[GXOFF + i] = expf(-d * d * a);
    }
    // gy table: bin centers c = -1 + (iy+0.5)*2/BY over (-1,1)
    for (int i = tid; i < HH * BY; i += stride) {
        const int h = i / BY, iy = i - h * BY;
        const float c = -1.0f + (iy + 0.5f) * (2.0f / BY);
        const float d = grid_y[h] - c;
        ws[GYOFF + i] = expf(-d * d * a);
    }
}

// ---------------------------------------------------------------------------
// Kernel 2: weighted 2D histogram (nearest bin), device-scope fp32 atomics.
// ---------------------------------------------------------------------------
__global__ void pie_hist(const float2* __restrict__ pairs,
                         float* __restrict__ hist, int n) {
    const int tid    = blockIdx.x * blockDim.x + threadIdx.x;
    const int stride = gridDim.x * blockDim.x;
    for (int i = tid; i < n; i += stride) {
        const float2 pr = pairs[i];
        const float b = pr.x;           // birth
        const float p = pr.y - pr.x;    // pers (== weight; can be negative)
        // norm divisors are 1.0f in fp32 (1 + 1e-8 rounds to 1), matching jnp f32
        int ix = (int)floorf(b * (float)BX);
        int iy = (int)floorf((p + 1.0f) * (0.5f * (float)BY));
        ix = min(max(ix, 0), BX - 1);
        iy = min(max(iy, 0), BY - 1);
        atomicAdd(&hist[iy * BX + ix], p);
    }
}

// ---------------------------------------------------------------------------
// Kernel 3: P[iy][w] = sum_ix hist[iy][ix] * gx_tab[w][ix]
// One block per 4 iy rows; hist rows staged in LDS (broadcast reads).
// ---------------------------------------------------------------------------
__global__ void pie_step1(const float* __restrict__ hist,
                          const float* __restrict__ gx_tab,
                          float* __restrict__ P) {
    __shared__ float lh[4 * BX];   // 8 KB
    const int iy0 = blockIdx.x * 4;
    for (int i = threadIdx.x; i < 4 * BX; i += blockDim.x)
        lh[i] = hist[iy0 * BX + i];
    __syncthreads();

    const int t = threadIdx.x;
    if (t < 4 * WW) {
        const int il = t / WW;        // local iy
        const int w  = t - il * WW;
        const float4* gx4 = (const float4*)(gx_tab + w * BX);
        const float4* lh4 = (const float4*)(lh + il * BX);
        float acc = 0.0f;
        #pragma unroll 4
        for (int k = 0; k < BX / 4; ++k) {
            const float4 g = gx4[k];
            const float4 h = lh4[k];
            acc += g.x * h.x + g.y * h.y + g.z * h.z + g.w * h.w;
        }
        P[(iy0 + il) * WW + w] = acc;
    }
}

// ---------------------------------------------------------------------------
// Kernel 4: img[h][w] = sum_iy gy_tab[h][iy] * P[iy][w]
// One block per h; K split over 4 thread groups, LDS reduce.
// ---------------------------------------------------------------------------
__global__ void pie_step2(const float* __restrict__ P,
                          const float* __restrict__ gy_tab,
                          float* __restrict__ img) {
    __shared__ float sacc[256];
    const int h = blockIdx.x;
    const int t = threadIdx.x;
    float acc = 0.0f;
    if (t < 4 * WW) {
        const int w  = t % WW;
        const int kc = t / WW;
        const float* gy = gy_tab + h * BY;
        const int iy0 = kc * (BY / 4);
        for (int iy = iy0; iy < iy0 + BY / 4; ++iy)
            acc += gy[iy] * P[iy * WW + w];
    }
    sacc[t] = acc;
    __syncthreads();
    if (t < WW)
        img[h * WW + t] = sacc[t] + sacc[t + WW] + sacc[t + 2 * WW] + sacc[t + 3 * WW];
}

// ---------------------------------------------------------------------------
// Kernel 5: out = img / (max(img) + eps), single block.
// ---------------------------------------------------------------------------
__global__ void pie_norm(const float* __restrict__ img, float* __restrict__ out) {
    __shared__ float smax[16];
    const int t = threadIdx.x;  // 1024 threads = 16 waves
    float m = -1e30f;
    for (int i = t; i < HH * WW; i += 1024) m = fmaxf(m, img[i]);
    #pragma unroll
    for (int off = 32; off > 0; off >>= 1)
        m = fmaxf(m, __shfl_down(m, off));
    const int wave = t >> 6, lane = t & 63;
    if (lane == 0) smax[wave] = m;
    __syncthreads();
    if (t == 0) {
        float mm = smax[0];
        for (int i = 1; i < 16; ++i) mm = fmaxf(mm, smax[i]);
        smax[0] = mm;
    }
    __syncthreads();
    const float inv = 1.0f / (smax[0] + EPSF);
    for (int i = t; i < HH * WW; i += 1024) out[i] = img[i] * inv;
}

// ---------------------------------------------------------------------------
extern "C" void kernel_launch(void* const* d_in, const int* in_sizes, int n_in,
                              void* d_out, int out_size, void* d_ws, size_t ws_size,
                              hipStream_t stream) {
    const float2* pairs  = (const float2*)d_in[0];
    const float*  sigma  = (const float*)d_in[1];
    const float*  grid_x = (const float*)d_in[2];
    const float*  grid_y = (const float*)d_in[3];
    float* ws  = (float*)d_ws;
    float* out = (float*)d_out;
    const int n = in_sizes[0] / 2;

    float* hist   = ws;
    float* gx_tab = ws + GXOFF;
    float* gy_tab = ws + GYOFF;
    float* P      = ws + POFF;
    float* img    = ws + IMGOFF;

    pie_init<<<512, 256, 0, stream>>>(ws, grid_x, grid_y, sigma);
    pie_hist<<<2048, 256, 0, stream>>>(pairs, hist, n);
    pie_step1<<<BY / 4, 256, 0, stream>>>(hist, gx_tab, P);
    pie_step2<<<HH, 256, 0, stream>>>(P, gy_tab, img);
    pie_norm<<<1, 1024, 0, stream>>>(img, out);
}

// Round 2
// 140.165 us; speedup vs baseline: 1.4153x; 1.4153x over previous
//
#include <hip/hip_runtime.h>

#define HH 50
#define WW 50
#define EPSF 1e-8f

// Histogram: x (birth) in [0,1] -> 128 bins; y (pers) in [-0.5, 1.0] -> 192 bins.
// Bilinear splat => per-factor error ~|G''|*d^2/8 = 100/(128^2*8) ~ 7.6e-4.
// p < -0.5 dropped: gy <= exp(-50*0.25) ~ 3.7e-6, negligible.
#define BXH 128
#define BYH 192
#define Y0F (-0.5f)
#define YSPAN 1.5f
#define REPSZ (BXH * BYH)          // 24576 floats = 96 KB per replica

// ws float offsets
#define GXOFF 0                     // gx_tab[w][ix]  : 50*128 = 6400
#define GYOFF (GXOFF + WW * BXH)    // gy_tab[h][iy]  : 50*192 = 9600
#define POFF  (GYOFF + HH * BYH)    // P[iy][w]       : 192*50 = 9600
#define REPOFF (POFF + BYH * WW)    // replicas       : R * 24576

// ---------------------------------------------------------------------------
__device__ __forceinline__ void splat(float b, float death, float* hist) {
    const float p = death - b;           // pers == weight
    if (p < Y0F) return;                 // negligible gy, drop
    const float fx = b * (float)BXH - 0.5f;
    const float fy = (p - Y0F) * ((float)BYH / YSPAN) - 0.5f;
    const float fx0 = floorf(fx), fy0 = floorf(fy);
    const float wx1 = fx - fx0, wy1 = fy - fy0;
    int ix0 = (int)fx0, iy0 = (int)fy0;
    const int ix1 = min(ix0 + 1, BXH - 1); ix0 = max(ix0, 0);
    const int iy1 = min(iy0 + 1, BYH - 1); iy0 = max(iy0, 0);
    const float py0 = p * (1.0f - wy1), py1 = p * wy1;
    atomicAdd(&hist[iy0 * BXH + ix0], py0 * (1.0f - wx1));
    atomicAdd(&hist[iy0 * BXH + ix1], py0 * wx1);
    atomicAdd(&hist[iy1 * BXH + ix0], py1 * (1.0f - wx1));
    atomicAdd(&hist[iy1 * BXH + ix1], py1 * wx1);
}

// ---------------------------------------------------------------------------
// K1: per-block private LDS histogram (bilinear splat), dump replica to ws.
// Block 0 additionally builds the exp lookup tables (overlapped; ~16 exps/thread).
// ---------------------------------------------------------------------------
__global__ __launch_bounds__(1024) void pie_hist_lds(
    const float4* __restrict__ pairs4, int n,
    const float* __restrict__ grid_x, const float* __restrict__ grid_y,
    const float* __restrict__ sigma_p, float* __restrict__ ws, int R)
{
    __shared__ float hist[REPSZ];        // 96 KB -> 1 block/CU, 16 waves
    const int t = threadIdx.x;

    #pragma unroll
    for (int i = t; i < REPSZ; i += 1024) hist[i] = 0.0f;

    if (blockIdx.x == 0) {
        const float s = *sigma_p;
        const float a = 1.0f / (2.0f * s * s);
        for (int i = t; i < WW * BXH; i += 1024) {
            const int w = i >> 7, ix = i & (BXH - 1);
            const float c = (ix + 0.5f) * (1.0f / BXH);
            const float d = grid_x[w] - c;
            ws[GXOFF + i] = __expf(-d * d * a);
        }
        for (int i = t; i < HH * BYH; i += 1024) {
            const int h = i / BYH, iy = i - h * BYH;
            const float c = Y0F + (iy + 0.5f) * (YSPAN / (float)BYH);
            const float d = grid_y[h] - c;
            ws[GYOFF + i] = __expf(-d * d * a);
        }
    }
    __syncthreads();

    const int n2 = n >> 1;               // two points per float4
    const int stride = R * 1024;
    #pragma unroll 2
    for (int i = blockIdx.x * 1024 + t; i < n2; i += stride) {
        const float4 q = pairs4[i];
        splat(q.x, q.y, hist);
        splat(q.z, q.w, hist);
    }
    if ((n & 1) && blockIdx.x == 0 && t == 0) {
        const float2 last = ((const float2*)pairs4)[n - 1];
        splat(last.x, last.y, hist);
    }
    __syncthreads();

    float4* dst = (float4*)(ws + REPOFF + (size_t)blockIdx.x * REPSZ);
    const float4* src = (const float4*)hist;
    #pragma unroll
    for (int i = t; i < REPSZ / 4; i += 1024) dst[i] = src[i];
}

// ---------------------------------------------------------------------------
// K2: one block per y-row. Merge R replicas for this row, then
//     P[row][w] = sum_ix hist_row[ix] * gx_tab[w][ix].
// ---------------------------------------------------------------------------
__global__ __launch_bounds__(1024) void pie_c1(float* __restrict__ ws, int R)
{
    __shared__ float part[8 * BXH];      // 4 KB
    __shared__ float row[BXH];
    __shared__ float gxl[WW * (BXH + 1)]; // padded stride 129: conflict-free dots
    const int t = threadIdx.x;
    const int rowi = blockIdx.x;

    for (int i = t; i < WW * BXH; i += 1024) {
        const int w = i >> 7, ix = i & (BXH - 1);
        gxl[w * (BXH + 1) + ix] = ws[GXOFF + i];
    }

    // merge: 8 replica-chunks x 128 ix = 1024 threads
    const int r0 = t >> 7;
    const int ix = t & (BXH - 1);
    const float* rep = ws + REPOFF + (size_t)rowi * BXH;
    float acc = 0.0f;
    #pragma unroll 4
    for (int r = r0; r < R; r += 8)
        acc += rep[(size_t)r * REPSZ + ix];
    part[r0 * BXH + ix] = acc;
    __syncthreads();

    if (t < BXH) {
        float s = 0.0f;
        #pragma unroll
        for (int k = 0; k < 8; ++k) s += part[k * BXH + t];
        row[t] = s;
    }
    __syncthreads();

    if (t < WW) {
        float accp = 0.0f;
        #pragma unroll 4
        for (int k = 0; k < BXH; ++k)
            accp += row[k] * gxl[t * (BXH + 1) + k];
        ws[POFF + rowi * WW + t] = accp;
    }
}

// ---------------------------------------------------------------------------
// K3: img[h][w] = sum_row gy[h][row] * P[row][w]; then out = img/(max+eps).
// Single block; all operands staged in LDS (~85 KB).
// ---------------------------------------------------------------------------
__global__ __launch_bounds__(1024) void pie_c2(const float* __restrict__ ws,
                                               float* __restrict__ out)
{
    __shared__ float gyl[HH * BYH];      // 37.5 KB
    __shared__ float Pl[BYH * WW];       // 37.5 KB
    __shared__ float img[HH * WW];       // 10 KB
    __shared__ float wmax[16];
    const int t = threadIdx.x;

    for (int i = t; i < HH * BYH; i += 1024) gyl[i] = ws[GYOFF + i];
    for (int i = t; i < BYH * WW; i += 1024) Pl[i] = ws[POFF + i];
    __syncthreads();

    for (int c = t; c < HH * WW; c += 1024) {
        const int h = c / WW, w = c - h * WW;
        float acc = 0.0f;
        #pragma unroll 4
        for (int r = 0; r < BYH; ++r)
            acc += gyl[h * BYH + r] * Pl[r * WW + w];
        img[c] = acc;
    }
    __syncthreads();

    float m = -1e30f;
    for (int c = t; c < HH * WW; c += 1024) m = fmaxf(m, img[c]);
    #pragma unroll
    for (int off = 32; off > 0; off >>= 1)
        m = fmaxf(m, __shfl_down(m, off));
    const int wv = t >> 6, ln = t & 63;
    if (ln == 0) wmax[wv] = m;
    __syncthreads();
    if (t == 0) {
        float mm = wmax[0];
        for (int k = 1; k < 16; ++k) mm = fmaxf(mm, wmax[k]);
        wmax[0] = mm;
    }
    __syncthreads();

    const float inv = 1.0f / (wmax[0] + EPSF);
    for (int c = t; c < HH * WW; c += 1024) out[c] = img[c] * inv;
}

// ---------------------------------------------------------------------------
extern "C" void kernel_launch(void* const* d_in, const int* in_sizes, int n_in,
                              void* d_out, int out_size, void* d_ws, size_t ws_size,
                              hipStream_t stream) {
    const float4* pairs4 = (const float4*)d_in[0];
    const float*  sigma  = (const float*)d_in[1];
    const float*  grid_x = (const float*)d_in[2];
    const float*  grid_y = (const float*)d_in[3];
    float* ws  = (float*)d_ws;
    float* out = (float*)d_out;
    const int n = in_sizes[0] / 2;

    // pick replica count from available workspace (round-1 evidence: ws >= 2.6 MB)
    const long avail = (long)(ws_size / sizeof(float));
    long cap = (avail - REPOFF) / REPSZ;
    int R = (int)(cap < 256 ? cap : 256);
    if (R < 8) R = 8;

    pie_hist_lds<<<R, 1024, 0, stream>>>(pairs4, n, grid_x, grid_y, sigma, ws, R);
    pie_c1<<<BYH, 1024, 0, stream>>>(ws, R);
    pie_c2<<<1, 1024, 0, stream>>>(ws, out);
}

// Round 3
// 115.452 us; speedup vs baseline: 1.7183x; 1.2141x over previous
//
#include <hip/hip_runtime.h>

#define HH 50
#define WW 50
#define EPSF 1e-8f

// Histogram: x (birth) in [0,1] -> 160 bins; y (pers) in [-0.5, 1.0] -> 240 bins.
// Nearest-bin splat (1 LDS atomic/point). delta = 1/160: smoothing bias
// ~|G''|d^2/24 ~ 1.6e-4; quantization noise cancels over ~1e5 points/footprint.
// p < -0.5 dropped: gy <= exp(-12.5) ~ 3.7e-6, negligible.
#define BXH 160
#define BYH 240
#define Y0F (-0.5f)
#define YSPAN 1.5f
#define REPSZ (BXH * BYH)            // 38400 bins; LDS 150 KB; bf16 replica 76.8 KB

// ws float offsets
#define GXOFF 0                       // gx_tab[w][ix] : 50*160 = 8000
#define GYOFF (GXOFF + WW * BXH)      // gy_tab[h][iy] : 50*240 = 12000
#define POFF  (GYOFF + HH * BYH)      // P[iy][w]      : 240*50 = 12000
#define REPOFF (POFF + BYH * WW)      // 32000 floats; bf16 replicas follow (16B aligned)

__device__ __forceinline__ unsigned bf16pk(float a, float b) {
    unsigned ua = __float_as_uint(a), ub = __float_as_uint(b);
    ua = (ua + 0x7FFFu + ((ua >> 16) & 1u)) >> 16;       // RNE
    ub = (ub + 0x7FFFu + ((ub >> 16) & 1u)) >> 16;
    return ua | (ub << 16);
}

__device__ __forceinline__ void splat1(float b, float death, float* hist) {
    const float p = death - b;               // pers == weight (may be negative)
    if (p < Y0F) return;
    int ix = (int)(b * (float)BXH);          // b >= 0: trunc == floor
    int iy = (int)((p - Y0F) * ((float)BYH / YSPAN));
    ix = min(ix, BXH - 1);
    iy = min(iy, BYH - 1);
    atomicAdd(&hist[iy * BXH + ix], p);
}

// ---------------------------------------------------------------------------
// K1: per-block private LDS histogram (nearest splat), dump replica as bf16.
// Block 0 additionally builds the exp lookup tables.
// ---------------------------------------------------------------------------
__global__ __launch_bounds__(1024) void pie_hist_lds(
    const float4* __restrict__ pairs4, int n,
    const float* __restrict__ grid_x, const float* __restrict__ grid_y,
    const float* __restrict__ sigma_p, float* __restrict__ ws, int R)
{
    __shared__ float hist[REPSZ];            // 150 KB -> 1 block/CU
    const int t = threadIdx.x;

    for (int i = t; i < REPSZ; i += 1024) hist[i] = 0.0f;

    if (blockIdx.x == 0) {
        const float s = *sigma_p;
        const float a = 1.0f / (2.0f * s * s);
        for (int i = t; i < WW * BXH; i += 1024) {
            const int w = i / BXH, ix = i - w * BXH;
            const float c = (ix + 0.5f) * (1.0f / BXH);
            const float d = grid_x[w] - c;
            ws[GXOFF + i] = __expf(-d * d * a);
        }
        for (int i = t; i < HH * BYH; i += 1024) {
            const int h = i / BYH, iy = i - h * BYH;
            const float c = Y0F + (iy + 0.5f) * (YSPAN / (float)BYH);
            const float d = grid_y[h] - c;
            ws[GYOFF + i] = __expf(-d * d * a);
        }
    }
    __syncthreads();

    const int n2 = n >> 1;                   // two points per float4
    const int stride = R * 1024;
    #pragma unroll 2
    for (int i = blockIdx.x * 1024 + t; i < n2; i += stride) {
        const float4 q = pairs4[i];
        splat1(q.x, q.y, hist);
        splat1(q.z, q.w, hist);
    }
    if ((n & 1) && blockIdx.x == 0 && t == 0) {
        const float2 last = ((const float2*)pairs4)[n - 1];
        splat1(last.x, last.y, hist);
    }
    __syncthreads();

    // dump as bf16 (uint2 = 4 bins per store)
    uint2* dst = (uint2*)((char*)(ws + REPOFF) + (size_t)blockIdx.x * (REPSZ * 2));
    const float4* src = (const float4*)hist;
    for (int i = t; i < REPSZ / 4; i += 1024) {
        const float4 v = src[i];
        uint2 o;
        o.x = bf16pk(v.x, v.y);
        o.y = bf16pk(v.z, v.w);
        dst[i] = o;
    }
}

// ---------------------------------------------------------------------------
// K2: one block per y-row. Merge R bf16 replicas for this row, then
//     P[row][w] = sum_ix row[ix] * gx_tab[w][ix].
// ---------------------------------------------------------------------------
__global__ __launch_bounds__(1024) void pie_c1(float* __restrict__ ws, int R)
{
    __shared__ float part[12 * BXH];         // 7.7 KB
    __shared__ float row[BXH];
    __shared__ float gxl[WW * (BXH + 1)];    // stride 161: conflict-free dot
    const int t = threadIdx.x;
    const int rowi = blockIdx.x;

    for (int i = t; i < WW * BXH; i += 1024) {
        const int w = i / BXH, ix = i - w * BXH;
        gxl[w * (BXH + 1) + ix] = ws[GXOFF + i];
    }

    // merge: 12 replica-groups x 80 bf16-pairs = 960 threads
    const int r0 = t / 80;                   // replica group
    const int px = t - r0 * 80;              // pair index within row
    if (r0 < 12) {
        const unsigned* repu = (const unsigned*)((char*)(ws + REPOFF)) + rowi * 80 + px;
        float alo = 0.0f, ahi = 0.0f;
        #pragma unroll 4
        for (int r = r0; r < R; r += 12) {
            const unsigned u = repu[(size_t)r * (REPSZ / 2)];
            alo += __uint_as_float(u << 16);
            ahi += __uint_as_float(u & 0xFFFF0000u);
        }
        part[r0 * BXH + 2 * px]     = alo;
        part[r0 * BXH + 2 * px + 1] = ahi;
    }
    __syncthreads();

    if (t < BXH) {
        float s = 0.0f;
        #pragma unroll
        for (int k = 0; k < 12; ++k) s += part[k * BXH + t];
        row[t] = s;
    }
    __syncthreads();

    if (t < WW) {
        float acc = 0.0f;
        #pragma unroll 4
        for (int k = 0; k < BXH; ++k)
            acc += row[k] * gxl[t * (BXH + 1) + k];
        ws[POFF + rowi * WW + t] = acc;
    }
}

// ---------------------------------------------------------------------------
// K3: img[h][w] = sum_row gy[h][row] * P[row][w]; then out = img/(max+eps).
// ---------------------------------------------------------------------------
__global__ __launch_bounds__(1024) void pie_c2(const float* __restrict__ ws,
                                               float* __restrict__ out)
{
    __shared__ float gyl[HH * BYH];          // 48 KB
    __shared__ float Pl[BYH * WW];           // 48 KB
    __shared__ float img[HH * WW];           // 10 KB
    __shared__ float wmax[16];
    const int t = threadIdx.x;

    for (int i = t; i < HH * BYH; i += 1024) gyl[i] = ws[GYOFF + i];
    for (int i = t; i < BYH * WW; i += 1024) Pl[i] = ws[POFF + i];
    __syncthreads();

    for (int c = t; c < HH * WW; c += 1024) {
        const int h = c / WW, w = c - h * WW;
        float acc = 0.0f;
        #pragma unroll 4
        for (int r = 0; r < BYH; ++r)
            acc += gyl[h * BYH + r] * Pl[r * WW + w];
        img[c] = acc;
    }
    __syncthreads();

    float m = -1e30f;
    for (int c = t; c < HH * WW; c += 1024) m = fmaxf(m, img[c]);
    #pragma unroll
    for (int off = 32; off > 0; off >>= 1)
        m = fmaxf(m, __shfl_down(m, off));
    const int wv = t >> 6, ln = t & 63;
    if (ln == 0) wmax[wv] = m;
    __syncthreads();
    if (t == 0) {
        float mm = wmax[0];
        for (int k = 1; k < 16; ++k) mm = fmaxf(mm, wmax[k]);
        wmax[0] = mm;
    }
    __syncthreads();

    const float inv = 1.0f / (wmax[0] + EPSF);
    for (int c = t; c < HH * WW; c += 1024) out[c] = img[c] * inv;
}

// ---------------------------------------------------------------------------
extern "C" void kernel_launch(void* const* d_in, const int* in_sizes, int n_in,
                              void* d_out, int out_size, void* d_ws, size_t ws_size,
                              hipStream_t stream) {
    const float4* pairs4 = (const float4*)d_in[0];
    const float*  sigma  = (const float*)d_in[1];
    const float*  grid_x = (const float*)d_in[2];
    const float*  grid_y = (const float*)d_in[3];
    float* ws  = (float*)d_ws;
    float* out = (float*)d_out;
    const int n = in_sizes[0] / 2;

    // replica count from available workspace (bf16 replicas: 76.8 KB each)
    const long avail_bytes = (long)ws_size - (long)REPOFF * 4;
    long cap = avail_bytes / (REPSZ * 2);
    int R = (int)(cap < 256 ? cap : 256);
    if (R < 1) R = 1;

    pie_hist_lds<<<R, 1024, 0, stream>>>(pairs4, n, grid_x, grid_y, sigma, ws, R);
    pie_c1<<<BYH, 1024, 0, stream>>>(ws, R);
    pie_c2<<<1, 1024, 0, stream>>>(ws, out);
}

// Round 4
// 107.125 us; speedup vs baseline: 1.8519x; 1.0777x over previous
//
#include <hip/hip_runtime.h>

#define HH 50
#define WW 50
#define EPSF 1e-8f

// Histogram: x (birth) in [0,1] -> 160 bins; y (pers) in [-0.5, 1.0] -> 240 bins.
// Nearest-bin splat (1 LDS atomic/point). p < -0.5 dropped: gy <= exp(-12.5).
#define BXH 160
#define BYH 240
#define Y0F (-0.5f)
#define YSPAN 1.5f
#define REPSZ (BXH * BYH)            // 38400 bins; LDS 150 KB; bf16 replica 76.8 KB

// ws float offsets
#define GXOFF 0                       // gx_tab[w][ix] : 50*160 = 8000
#define GYOFF (GXOFF + WW * BXH)      // gy_tab[h][iy] : 50*240 = 12000
#define POFF  (GYOFF + HH * BYH)      // P[iy][w]      : 240*50 = 12000
#define IMGOFF (POFF + BYH * WW)      // img           : 2500
#define CNTOFF (IMGOFF + HH * WW + 12) // int ticket counter (padded)
#define REPOFF (CNTOFF + 4)           // 16B-aligned; bf16 replicas follow

__device__ __forceinline__ unsigned bf16pk(float a, float b) {
    unsigned ua = __float_as_uint(a), ub = __float_as_uint(b);
    ua = (ua + 0x7FFFu + ((ua >> 16) & 1u)) >> 16;       // RNE
    ub = (ub + 0x7FFFu + ((ub >> 16) & 1u)) >> 16;
    return ua | (ub << 16);
}

__device__ __forceinline__ void splat1(float b, float death, float* hist) {
    const float p = death - b;               // pers == weight (may be negative)
    if (p < Y0F) return;
    int ix = (int)(b * (float)BXH);          // b >= 0: trunc == floor
    int iy = (int)((p - Y0F) * ((float)BYH / YSPAN));
    ix = min(ix, BXH - 1);
    iy = min(iy, BYH - 1);
    atomicAdd(&hist[iy * BXH + ix], p);
}

// ---------------------------------------------------------------------------
// K1: per-block private LDS histogram (nearest splat), dump replica as bf16.
// Block 0 additionally builds the exp lookup tables + zeroes the K3 ticket.
// ---------------------------------------------------------------------------
__global__ __launch_bounds__(1024) void pie_hist_lds(
    const float4* __restrict__ pairs4, int n,
    const float* __restrict__ grid_x, const float* __restrict__ grid_y,
    const float* __restrict__ sigma_p, float* __restrict__ ws, int R)
{
    __shared__ float hist[REPSZ];            // 150 KB -> 1 block/CU
    const int t = threadIdx.x;

    for (int i = t; i < REPSZ; i += 1024) hist[i] = 0.0f;

    if (blockIdx.x == 0) {
        if (t == 0) ((int*)ws)[CNTOFF] = 0;  // K3 ticket (visible at K3 via dispatch order)
        const float s = *sigma_p;
        const float a = 1.0f / (2.0f * s * s);
        for (int i = t; i < WW * BXH; i += 1024) {
            const int w = i / BXH, ix = i - w * BXH;
            const float c = (ix + 0.5f) * (1.0f / BXH);
            const float d = grid_x[w] - c;
            ws[GXOFF + i] = __expf(-d * d * a);
        }
        for (int i = t; i < HH * BYH; i += 1024) {
            const int h = i / BYH, iy = i - h * BYH;
            const float c = Y0F + (iy + 0.5f) * (YSPAN / (float)BYH);
            const float d = grid_y[h] - c;
            ws[GYOFF + i] = __expf(-d * d * a);
        }
    }
    __syncthreads();

    const int n2 = n >> 1;                   // two points per float4
    const int stride = R * 1024;
    #pragma unroll 2
    for (int i = blockIdx.x * 1024 + t; i < n2; i += stride) {
        const float4 q = pairs4[i];
        splat1(q.x, q.y, hist);
        splat1(q.z, q.w, hist);
    }
    if ((n & 1) && blockIdx.x == 0 && t == 0) {
        const float2 last = ((const float2*)pairs4)[n - 1];
        splat1(last.x, last.y, hist);
    }
    __syncthreads();

    // dump as bf16 (uint2 = 4 bins per store)
    uint2* dst = (uint2*)((char*)ws + (size_t)REPOFF * 4 + (size_t)blockIdx.x * (REPSZ * 2));
    const float4* src = (const float4*)hist;
    for (int i = t; i < REPSZ / 4; i += 1024) {
        const float4 v = src[i];
        uint2 o;
        o.x = bf16pk(v.x, v.y);
        o.y = bf16pk(v.z, v.w);
        dst[i] = o;
    }
}

// ---------------------------------------------------------------------------
// K2: one block per y-row. Merge R bf16 replicas for this row (uint2 = 4 bins
// per load), then P[row][w] = sum_ix row[ix] * gx_tab[w][ix].
// 640 threads: 16 replica-groups x 40 uint2 slots.
// ---------------------------------------------------------------------------
__global__ __launch_bounds__(640) void pie_c1(float* __restrict__ ws, int R)
{
    __shared__ float part[16 * BXH];         // 10 KB
    __shared__ float row[BXH];
    __shared__ float gxl[WW * (BXH + 1)];    // stride 161: conflict-free dot
    const int t = threadIdx.x;
    const int rowi = blockIdx.x;

    for (int i = t; i < WW * BXH; i += 640) {
        const int w = i / BXH, ix = i - w * BXH;
        gxl[w * (BXH + 1) + ix] = ws[GXOFF + i];
    }

    const int g = t / 40;                    // replica group 0..15
    const int s = t - g * 40;                // uint2 slot within row (4 bins)
    {
        const char* repbase = (const char*)ws + (size_t)REPOFF * 4;
        float a0 = 0.0f, a1 = 0.0f, a2 = 0.0f, a3 = 0.0f;
        #pragma unroll 4
        for (int r = g; r < R; r += 16) {
            const uint2 u = *(const uint2*)(repbase + (size_t)r * (REPSZ * 2)
                                            + (size_t)(rowi * 40 + s) * 8);
            a0 += __uint_as_float(u.x << 16);
            a1 += __uint_as_float(u.x & 0xFFFF0000u);
            a2 += __uint_as_float(u.y << 16);
            a3 += __uint_as_float(u.y & 0xFFFF0000u);
        }
        ((float4*)part)[g * 40 + s] = make_float4(a0, a1, a2, a3);
    }
    __syncthreads();

    if (t < BXH) {
        float sum = 0.0f;
        #pragma unroll
        for (int k = 0; k < 16; ++k) sum += part[k * BXH + t];
        row[t] = sum;
    }
    __syncthreads();

    if (t < WW) {
        float acc = 0.0f;
        #pragma unroll 4
        for (int k = 0; k < BXH; ++k)
            acc += row[k] * gxl[t * (BXH + 1) + k];
        ws[POFF + rowi * WW + t] = acc;
    }
}

// ---------------------------------------------------------------------------
// K3: 50 blocks, block h: img[h][w] = sum_r gy[h][r] * P[r][w].
// Last-done block (device atomic ticket) computes max + normalize + writes out.
// ---------------------------------------------------------------------------
__global__ __launch_bounds__(256) void pie_c2(float* __restrict__ ws,
                                              float* __restrict__ out)
{
    __shared__ float part[5 * WW];
    __shared__ float redmax[4];
    __shared__ int is_last;
    const int h = blockIdx.x;
    const int t = threadIdx.x;

    if (t < 5 * WW) {
        const int w = t % WW;
        const int c = t / WW;                // 0..4, 48 rows each
        const float* gy = ws + GYOFF + h * BYH;
        const float* P  = ws + POFF;
        const int r0 = c * (BYH / 5);
        float acc = 0.0f;
        #pragma unroll 4
        for (int r = r0; r < r0 + BYH / 5; ++r)
            acc += gy[r] * P[r * WW + w];
        part[t] = acc;
    }
    __syncthreads();
    if (t < WW)
        ws[IMGOFF + h * WW + t] = part[t] + part[WW + t] + part[2 * WW + t]
                                + part[3 * WW + t] + part[4 * WW + t];
    __threadfence();                         // release img row before ticket
    __syncthreads();
    if (t == 0) {
        const int old = atomicAdd((int*)ws + CNTOFF, 1);
        is_last = (old == HH - 1);
    }
    __syncthreads();
    if (!is_last) return;
    __threadfence();                         // acquire all img rows

    float m = -1e30f;
    for (int i = t; i < HH * WW; i += 256) m = fmaxf(m, ws[IMGOFF + i]);
    #pragma unroll
    for (int off = 32; off > 0; off >>= 1)
        m = fmaxf(m, __shfl_down(m, off));
    const int wv = t >> 6, ln = t & 63;
    if (ln == 0) redmax[wv] = m;
    __syncthreads();
    if (t == 0)
        redmax[0] = fmaxf(fmaxf(redmax[0], redmax[1]), fmaxf(redmax[2], redmax[3]));
    __syncthreads();

    const float inv = 1.0f / (redmax[0] + EPSF);
    for (int i = t; i < HH * WW; i += 256) out[i] = ws[IMGOFF + i] * inv;
}

// ---------------------------------------------------------------------------
extern "C" void kernel_launch(void* const* d_in, const int* in_sizes, int n_in,
                              void* d_out, int out_size, void* d_ws, size_t ws_size,
                              hipStream_t stream) {
    const float4* pairs4 = (const float4*)d_in[0];
    const float*  sigma  = (const float*)d_in[1];
    const float*  grid_x = (const float*)d_in[2];
    const float*  grid_y = (const float*)d_in[3];
    float* ws  = (float*)d_ws;
    float* out = (float*)d_out;
    const int n = in_sizes[0] / 2;

    // replica count from available workspace (bf16 replicas: 76.8 KB each)
    const long avail_bytes = (long)ws_size - (long)REPOFF * 4;
    long cap = avail_bytes / (REPSZ * 2);
    int R = (int)(cap < 256 ? cap : 256);
    if (R < 1) R = 1;

    pie_hist_lds<<<R, 1024, 0, stream>>>(pairs4, n, grid_x, grid_y, sigma, ws, R);
    pie_c1<<<BYH, 640, 0, stream>>>(ws, R);
    pie_c2<<<HH, 256, 0, stream>>>(ws, out);
}